// Round 8
// baseline (253.297 us; speedup 1.0000x reference)
//
#include <hip/hip_runtime.h>
#include <hip/hip_bf16.h>
#include <math.h>

#define N_NODES 50000
#define N_EDGES 800000
#define IN_F 256
#define HD 128   // H*D
#define NHEAD 4
#define NB_SCAN 196   // ceil(50000/256)
#define GBM 64        // GEMM rows per block

typedef __attribute__((ext_vector_type(8))) short bf16x8;
typedef __attribute__((ext_vector_type(4))) float f32x4;

__device__ __forceinline__ float lrelu(float x){ return x > 0.f ? x : 0.2f * x; }

__device__ __forceinline__ unsigned short f32_to_bf16_rn(float x){
    union { float f; unsigned int u; } v; v.f = x;
    unsigned int r = v.u + 0x7FFFu + ((v.u >> 16) & 1u);
    return (unsigned short)(r >> 16);
}
__device__ __forceinline__ float bf16_to_f32(unsigned short h){
    union { unsigned int u; float f; } v; v.u = ((unsigned int)h) << 16;
    return v.f;
}
__device__ __forceinline__ float bflo(unsigned int u){
    union { unsigned int x; float f; } v; v.x = u << 16; return v.f;
}
__device__ __forceinline__ float bfhi(unsigned int u){
    union { unsigned int x; float f; } v; v.x = u & 0xFFFF0000u; return v.f;
}

// ---------------- fused: zero deg + W pre-transpose/split ----------------
__global__ __launch_bounds__(256) void prep_kernel(const float* __restrict__ W,
                                                   unsigned short* __restrict__ Wt_hi,
                                                   unsigned short* __restrict__ Wt_lo,
                                                   int* __restrict__ deg){
    int b = blockIdx.x;
    if (b < NB_SCAN){
        int i = b * 256 + threadIdx.x;
        if (i < N_NODES) deg[i] = 0;
    } else {
        int gid = (b - NB_SCAN) * 256 + threadIdx.x;   // 32768 total
        int n = gid >> 8;
        int k = gid & 255;
        float x = W[(size_t)k * HD + n];
        unsigned short h = f32_to_bf16_rn(x);
        float r = x - bf16_to_f32(h);
        Wt_hi[gid] = h;
        Wt_lo[gid] = f32_to_bf16_rn(r);
    }
}

// ---------------- GEMM: barrier-free, LDS-free; B frags from L2 ----------------
// 256 thr = 4 waves; wave owns 16 rows, all 8 n-frags. A double-buffered in regs.
__global__ __launch_bounds__(256, 4) void gemm_kernel(const float* __restrict__ feat,
                                                      const unsigned short* __restrict__ Wt_hi,
                                                      const unsigned short* __restrict__ Wt_lo,
                                                      const float* __restrict__ attn_l,
                                                      const float* __restrict__ attn_r,
                                                      unsigned short* __restrict__ ftb,
                                                      float* __restrict__ el,
                                                      float* __restrict__ er){
    const int tid  = threadIdx.x;
    const int lane = tid & 63;
    const int wv   = tid >> 6;            // 0..3
    const int r    = lane & 15;           // A/B frag row/col within 16
    const int g    = lane >> 4;           // k-subgroup 0..3
    const int arow = blockIdx.x * GBM + wv * 16 + r;
    const bool rowok = (arow < N_NODES);
    const float* arp = feat + (size_t)arow * IN_F + g * 8;
    const unsigned short* bhp = Wt_hi + r * 256 + g * 8;   // + nf*4096 + t*32
    const unsigned short* blp = Wt_lo + r * 256 + g * 8;

    f32x4 acc[8];
#pragma unroll
    for (int j = 0; j < 8; ++j) acc[j] = (f32x4){0.f, 0.f, 0.f, 0.f};

    float4 a0 = make_float4(0.f,0.f,0.f,0.f), a1 = a0;
    if (rowok){ a0 = *(const float4*)(arp); a1 = *(const float4*)(arp + 4); }

#pragma unroll
    for (int t = 0; t < 8; ++t){          // t = kc*2+kb, K chunk of 32
        float4 n0 = make_float4(0.f,0.f,0.f,0.f), n1 = n0;
        if (t < 7 && rowok){
            n0 = *(const float4*)(arp + (t + 1) * 32);
            n1 = *(const float4*)(arp + (t + 1) * 32 + 4);
        }
        float av[8] = {a0.x, a0.y, a0.z, a0.w, a1.x, a1.y, a1.z, a1.w};
        bf16x8 ah, al;
#pragma unroll
        for (int j = 0; j < 8; ++j){
            unsigned short h = f32_to_bf16_rn(av[j]);
            ah[j] = (short)h;
            al[j] = (short)f32_to_bf16_rn(av[j] - bf16_to_f32(h));
        }
        const unsigned short* bh_t = bhp + t * 32;
        const unsigned short* bl_t = blp + t * 32;
#pragma unroll
        for (int nf = 0; nf < 8; ++nf){
            bf16x8 bh = *(const bf16x8*)(bh_t + nf * 4096);
            bf16x8 bl = *(const bf16x8*)(bl_t + nf * 4096);
            acc[nf] = __builtin_amdgcn_mfma_f32_16x16x32_bf16(ah, bh, acc[nf], 0, 0, 0);
            acc[nf] = __builtin_amdgcn_mfma_f32_16x16x32_bf16(ah, bl, acc[nf], 0, 0, 0);
            acc[nf] = __builtin_amdgcn_mfma_f32_16x16x32_bf16(al, bh, acc[nf], 0, 0, 0);
        }
        a0 = n0; a1 = n1;
    }
    // ---- epilogue: C/D layout col=(lane&15)+nf*16, row=wv*16+(lane>>4)*4+reg ----
    float alv[8], arv[8];
#pragma unroll
    for (int nf = 0; nf < 8; ++nf){
        alv[nf] = attn_l[r + nf * 16];
        arv[nf] = attn_r[r + nf * 16];
    }
    const int g4 = g * 4;
#pragma unroll
    for (int rg = 0; rg < 4; ++rg){
        int gr = blockIdx.x * GBM + wv * 16 + g4 + rg;
        if (gr < N_NODES){
            unsigned short* op = ftb + (size_t)gr * HD + r;
#pragma unroll
            for (int nf = 0; nf < 8; ++nf) op[nf * 16] = f32_to_bf16_rn(acc[nf][rg]);
        }
        float pl0 = acc[0][rg] * alv[0] + acc[1][rg] * alv[1];
        float pl1 = acc[2][rg] * alv[2] + acc[3][rg] * alv[3];
        float pl2 = acc[4][rg] * alv[4] + acc[5][rg] * alv[5];
        float pl3 = acc[6][rg] * alv[6] + acc[7][rg] * alv[7];
        float pr0 = acc[0][rg] * arv[0] + acc[1][rg] * arv[1];
        float pr1 = acc[2][rg] * arv[2] + acc[3][rg] * arv[3];
        float pr2 = acc[4][rg] * arv[4] + acc[5][rg] * arv[5];
        float pr3 = acc[6][rg] * arv[6] + acc[7][rg] * arv[7];
#pragma unroll
        for (int m = 1; m <= 8; m <<= 1){
            pl0 += __shfl_xor(pl0, m, 64); pl1 += __shfl_xor(pl1, m, 64);
            pl2 += __shfl_xor(pl2, m, 64); pl3 += __shfl_xor(pl3, m, 64);
            pr0 += __shfl_xor(pr0, m, 64); pr1 += __shfl_xor(pr1, m, 64);
            pr2 += __shfl_xor(pr2, m, 64); pr3 += __shfl_xor(pr3, m, 64);
        }
        if (r == 0 && gr < N_NODES){
            *(float4*)(el + (size_t)gr * NHEAD) = make_float4(pl0, pl1, pl2, pl3);
            *(float4*)(er + (size_t)gr * NHEAD) = make_float4(pr0, pr1, pr2, pr3);
        }
    }
}

// ---------------- CSR build: degree + rank in one pass ----------------
__global__ void degree_kernel(const int* __restrict__ dst, int* __restrict__ deg,
                              int* __restrict__ rank){
    int e = blockIdx.x * blockDim.x + threadIdx.x;
    if (e < N_EDGES) rank[e] = atomicAdd(&deg[dst[e]], 1);
}

// hierarchical scan: part -> mid -> add
__global__ __launch_bounds__(256) void scan_part(const int* __restrict__ deg,
                                                 int* __restrict__ row_off,
                                                 int* __restrict__ blk_sums){
    __shared__ int lds[256];
    int tid = threadIdx.x;
    int i = blockIdx.x * 256 + tid;
    int v = (i < N_NODES) ? deg[i] : 0;
    int x = v;
    lds[tid] = x;
    __syncthreads();
    for (int off = 1; off < 256; off <<= 1){
        int t = (tid >= off) ? lds[tid - off] : 0;
        __syncthreads();
        x += t;
        lds[tid] = x;
        __syncthreads();
    }
    if (i < N_NODES) row_off[i] = x - v;          // local exclusive
    if (tid == 255) blk_sums[blockIdx.x] = x;     // block total
}

__global__ __launch_bounds__(256) void scan_mid(int* __restrict__ blk_sums,
                                                int* __restrict__ blk_off){
    __shared__ int lds[256];
    int tid = threadIdx.x;
    int v = (tid < NB_SCAN) ? blk_sums[tid] : 0;
    int x = v;
    lds[tid] = x;
    __syncthreads();
    for (int off = 1; off < 256; off <<= 1){
        int t = (tid >= off) ? lds[tid - off] : 0;
        __syncthreads();
        x += t;
        lds[tid] = x;
        __syncthreads();
    }
    blk_off[tid] = x - v;                          // exclusive
}

__global__ __launch_bounds__(256) void scan_add(int* __restrict__ row_off,
                                                const int* __restrict__ blk_off){
    int i = blockIdx.x * 256 + threadIdx.x;
    if (i < N_NODES) row_off[i] += blk_off[blockIdx.x];
    if (blockIdx.x == 0 && threadIdx.x == 0) row_off[N_NODES] = N_EDGES;
}

// ---------------- scatter: atomic-free, 4B per edge ----------------
__global__ void scatter_kernel(const int* __restrict__ src, const int* __restrict__ dst,
                               const int* __restrict__ rank, const int* __restrict__ row_off,
                               int* __restrict__ csr_src){
    int e = blockIdx.x * blockDim.x + threadIdx.x;
    if (e >= N_EDGES) return;
    csr_src[row_off[dst[e]] + rank[e]] = src[e];
}

// ---------------- aggregation: 16 nodes/block, one 16-lane group per node ----------------
// lane l of a group covers cols 8l..8l+7 (one uint4 per edge); head h = l>>2.
// Per-edge weight broadcast via per-group LDS chunk (16 edges). No cross-lane reduce needed.
__global__ __launch_bounds__(256) void aggregate_kernel(const unsigned short* __restrict__ ftb,
                                                        const int* __restrict__ csr_src,
                                                        const float* __restrict__ el,
                                                        const float* __restrict__ er,
                                                        const int* __restrict__ row_off,
                                                        const float* __restrict__ bias,
                                                        float* __restrict__ out){
    __shared__ float lw[4][4][16][4];   // [wave][grp][edge][head]
    __shared__ int   ls[4][4][16];      // [wave][grp][edge]

    const int wv   = threadIdx.x >> 6;
    const int lane = threadIdx.x & 63;
    const int grp  = lane >> 4;
    const int l    = lane & 15;
    const int h    = l >> 2;
    const int n    = blockIdx.x * 16 + wv * 4 + grp;     // grid 3125*16 = 50000 exact
    const int beg  = row_off[n], end = row_off[n + 1];
    const float4 ern = *(const float4*)(er + (size_t)n * NHEAD);

    float a[8];
#pragma unroll
    for (int k = 0; k < 8; ++k) a[k] = 0.f;
    float wsum = 0.f;

    for (int base = beg; base < end; base += 16){
        int cnt = end - base; if (cnt > 16) cnt = 16;
        if (l < cnt){
            int s_l = csr_src[base + l];
            float4 elv = *(const float4*)(el + (size_t)s_l * NHEAD);
            float4 w4;
            w4.x = __expf(lrelu(elv.x + ern.x));
            w4.y = __expf(lrelu(elv.y + ern.y));
            w4.z = __expf(lrelu(elv.z + ern.z));
            w4.w = __expf(lrelu(elv.w + ern.w));
            ls[wv][grp][l] = s_l;
            *(float4*)(&lw[wv][grp][l][0]) = w4;
        }
        asm volatile("s_waitcnt lgkmcnt(0)" ::: "memory");
        __builtin_amdgcn_sched_barrier(0);
        for (int j = 0; j < cnt; ++j){
            float w = lw[wv][grp][j][h];
            int   s = ls[wv][grp][j];
            uint4 f = *(const uint4*)(ftb + (size_t)s * HD + 8 * l);
            a[0] += w * bflo(f.x); a[1] += w * bfhi(f.x);
            a[2] += w * bflo(f.y); a[3] += w * bfhi(f.y);
            a[4] += w * bflo(f.z); a[5] += w * bfhi(f.z);
            a[6] += w * bflo(f.w); a[7] += w * bfhi(f.w);
            wsum += w;
        }
        __builtin_amdgcn_sched_barrier(0);        // keep next chunk's ds_write after reads
    }
    float inv = (end > beg) ? 1.f / wsum : 0.f;
    float4 b0 = *(const float4*)(bias + 8 * l);
    float4 b1 = *(const float4*)(bias + 8 * l + 4);
    float4 o0, o1;
    o0.x = a[0] * inv + b0.x; o0.y = a[1] * inv + b0.y;
    o0.z = a[2] * inv + b0.z; o0.w = a[3] * inv + b0.w;
    o1.x = a[4] * inv + b1.x; o1.y = a[5] * inv + b1.y;
    o1.z = a[6] * inv + b1.z; o1.w = a[7] * inv + b1.w;
    *(float4*)(out + (size_t)n * HD + 8 * l)     = o0;
    *(float4*)(out + (size_t)n * HD + 8 * l + 4) = o1;
}

extern "C" void kernel_launch(void* const* d_in, const int* in_sizes, int n_in,
                              void* d_out, int out_size, void* d_ws, size_t ws_size,
                              hipStream_t stream){
    const float* feat   = (const float*)d_in[0];
    const int*   src    = (const int*)  d_in[1];
    const int*   dst    = (const int*)  d_in[2];
    const float* W      = (const float*)d_in[3];
    const float* attn_l = (const float*)d_in[4];
    const float* attn_r = (const float*)d_in[5];
    const float* bias   = (const float*)d_in[6];
    float* out = (float*)d_out;
    char*  ws  = (char*)d_ws;

    // workspace layout (bytes)
    unsigned short* ftb = (unsigned short*)(ws + 0);   // 12,800,000
    float* el      = (float*)(ws + 12800000);   // 800,000
    float* er      = (float*)(ws + 13600000);   // 800,000
    int*   deg     = (int*)  (ws + 14400000);   // 200,000
    int*   rank    = (int*)  (ws + 14600000);   // 3,200,000
    int*   row_off = (int*)  (ws + 17800000);   // 200,004 (pad to 200,064)
    int*   csr_src = (int*)  (ws + 18000064);   // 3,200,000
    unsigned short* Wt_hi = (unsigned short*)(ws + 21200064);  // 65,536
    unsigned short* Wt_lo = (unsigned short*)(ws + 21265600);  // 65,536 (total ~21.3 MB)

    // transient aliases (scan-time only, csr_src not yet written):
    int* blk_sums = (int*)csr_src;
    int* blk_off  = blk_sums + 256;

    prep_kernel<<<NB_SCAN + 128, 256, 0, stream>>>(W, Wt_hi, Wt_lo, deg);
    gemm_kernel<<<(N_NODES + GBM - 1) / GBM, 256, 0, stream>>>(feat, Wt_hi, Wt_lo,
                                                               attn_l, attn_r, ftb, el, er);
    degree_kernel<<<(N_EDGES + 255) / 256, 256, 0, stream>>>(dst, deg, rank);
    scan_part<<<NB_SCAN, 256, 0, stream>>>(deg, row_off, blk_sums);
    scan_mid<<<1, 256, 0, stream>>>(blk_sums, blk_off);
    scan_add<<<NB_SCAN, 256, 0, stream>>>(row_off, blk_off);
    scatter_kernel<<<(N_EDGES + 255) / 256, 256, 0, stream>>>(src, dst, rank, row_off, csr_src);
    aggregate_kernel<<<N_NODES / 16, 256, 0, stream>>>(ftb, csr_src, el, er,
                                                       row_off, bias, out);
}

// Round 12
// 207.665 us; speedup vs baseline: 1.2197x; 1.2197x over previous
//
#include <hip/hip_runtime.h>
#include <hip/hip_bf16.h>
#include <math.h>

#define N_NODES 50000
#define N_EDGES 800000
#define IN_F 256
#define HD 128   // H*D
#define NHEAD 4
#define NB_SCAN 196   // ceil(50000/256)
#define GBM 64        // GEMM rows per block

typedef __attribute__((ext_vector_type(8))) short bf16x8;
typedef __attribute__((ext_vector_type(4))) float f32x4;

__device__ __forceinline__ float lrelu(float x){ return x > 0.f ? x : 0.2f * x; }

__device__ __forceinline__ unsigned short f32_to_bf16_rn(float x){
    union { float f; unsigned int u; } v; v.f = x;
    unsigned int r = v.u + 0x7FFFu + ((v.u >> 16) & 1u);
    return (unsigned short)(r >> 16);
}
__device__ __forceinline__ float bf16_to_f32(unsigned short h){
    union { unsigned int u; float f; } v; v.u = ((unsigned int)h) << 16;
    return v.f;
}
__device__ __forceinline__ float bflo(unsigned int u){
    union { unsigned int x; float f; } v; v.x = u << 16; return v.f;
}
__device__ __forceinline__ float bfhi(unsigned int u){
    union { unsigned int x; float f; } v; v.x = u & 0xFFFF0000u; return v.f;
}

// ---------------- fused: zero deg + W pre-transpose/split (hi only) ----------------
__global__ __launch_bounds__(256) void prep_kernel(const float* __restrict__ W,
                                                   unsigned short* __restrict__ Wt_hi,
                                                   int* __restrict__ deg){
    int b = blockIdx.x;
    if (b < NB_SCAN){
        int i = b * 256 + threadIdx.x;
        if (i < N_NODES) deg[i] = 0;
    } else {
        int gid = (b - NB_SCAN) * 256 + threadIdx.x;   // 32768 total
        int n = gid >> 8;
        int k = gid & 255;
        Wt_hi[gid] = f32_to_bf16_rn(W[(size_t)k * HD + n]);
    }
}

// ---------------- GEMM: ftb[N,128](bf16) = feat[N,256] @ W[256,128], fused el/er ----------------
// 256 thr = 4 waves; wave owns 16 rows, all 8 n-frags.
// A: global->reg, prefetched one kc ahead, bf16 hi/lo in regs (2-term MFMA vs bf16 W).
// B: frag-major LDS, conflict-free writes (u = i*256+tid) and reads.
__global__ __launch_bounds__(256, 4) void gemm_kernel(const float* __restrict__ feat,
                                                      const unsigned short* __restrict__ Wt_hi,
                                                      const float* __restrict__ attn_l,
                                                      const float* __restrict__ attn_r,
                                                      unsigned short* __restrict__ ftb,
                                                      float* __restrict__ el,
                                                      float* __restrict__ er){
    __shared__ unsigned short Bh[2][8][64][8];   // [kb][nf][lane][8] = 16KB

    const int tid  = threadIdx.x;
    const int lane = tid & 63;
    const int wv   = tid >> 6;            // 0..3
    const int r    = lane & 15;           // frag row within 16
    const int g    = lane >> 4;           // k-subgroup 0..3
    const int arow = blockIdx.x * GBM + wv * 16 + r;
    const bool rowok = (arow < N_NODES);
    const float* arp = feat + (size_t)arow * IN_F + g * 8;

    f32x4 acc[8];
#pragma unroll
    for (int j = 0; j < 8; ++j) acc[j] = (f32x4){0.f, 0.f, 0.f, 0.f};

    // A regs for current kc: [kb0:{0,1}, kb1:{2,3}]
    float4 a[4];
#pragma unroll
    for (int j = 0; j < 4; ++j) a[j] = make_float4(0.f, 0.f, 0.f, 0.f);
    if (rowok){
        a[0] = *(const float4*)(arp);      a[1] = *(const float4*)(arp + 4);
        a[2] = *(const float4*)(arp + 32); a[3] = *(const float4*)(arp + 36);
    }

    for (int kc = 0; kc < 4; ++kc){
        const int k0 = kc * 64;
        // ---- stage B frag-major, conflict-free: instr i writes unit i*256+tid ----
#pragma unroll
        for (int i = 0; i < 4; ++i){
            int u  = i * 256 + tid;
            int l2 = u & 63;
            int fn = (u >> 6) & 7;
            int kb = u >> 9;
            int nn = fn * 16 + (l2 & 15);
            int kk = k0 + kb * 32 + (l2 >> 4) * 8;
            *(uint4*)(&Bh[kb][fn][l2][0]) = *(const uint4*)(Wt_hi + nn * 256 + kk);
        }
        __syncthreads();
        // ---- prefetch next kc's A while computing this one ----
        float4 n[4];
#pragma unroll
        for (int j = 0; j < 4; ++j) n[j] = make_float4(0.f, 0.f, 0.f, 0.f);
        if (kc < 3 && rowok){
            const float* np = arp + (kc + 1) * 64;
            n[0] = *(const float4*)(np);      n[1] = *(const float4*)(np + 4);
            n[2] = *(const float4*)(np + 32); n[3] = *(const float4*)(np + 36);
        }
#pragma unroll
        for (int kb = 0; kb < 2; ++kb){
            float av[8] = {a[2*kb].x, a[2*kb].y, a[2*kb].z, a[2*kb].w,
                           a[2*kb+1].x, a[2*kb+1].y, a[2*kb+1].z, a[2*kb+1].w};
            bf16x8 ah, al;
#pragma unroll
            for (int j = 0; j < 8; ++j){
                unsigned short h = f32_to_bf16_rn(av[j]);
                ah[j] = (short)h;
                al[j] = (short)f32_to_bf16_rn(av[j] - bf16_to_f32(h));
            }
#pragma unroll
            for (int nf = 0; nf < 8; ++nf){
                bf16x8 bh = *(const bf16x8*)(&Bh[kb][nf][lane][0]);
                acc[nf] = __builtin_amdgcn_mfma_f32_16x16x32_bf16(ah, bh, acc[nf], 0, 0, 0);
                acc[nf] = __builtin_amdgcn_mfma_f32_16x16x32_bf16(al, bh, acc[nf], 0, 0, 0);
            }
        }
        __syncthreads();
#pragma unroll
        for (int j = 0; j < 4; ++j) a[j] = n[j];
    }
    // ---- epilogue: C/D layout col=(lane&15)+nf*16, row=wv*16+(lane>>4)*4+reg ----
    float alv[8], arv[8];
#pragma unroll
    for (int nf = 0; nf < 8; ++nf){
        alv[nf] = attn_l[r + nf * 16];
        arv[nf] = attn_r[r + nf * 16];
    }
    const int g4 = g * 4;
#pragma unroll
    for (int rg = 0; rg < 4; ++rg){
        int gr = blockIdx.x * GBM + wv * 16 + g4 + rg;
        if (gr < N_NODES){
            unsigned short* op = ftb + (size_t)gr * HD + r;
#pragma unroll
            for (int nf = 0; nf < 8; ++nf) op[nf * 16] = f32_to_bf16_rn(acc[nf][rg]);
        }
        float pl0 = acc[0][rg] * alv[0] + acc[1][rg] * alv[1];
        float pl1 = acc[2][rg] * alv[2] + acc[3][rg] * alv[3];
        float pl2 = acc[4][rg] * alv[4] + acc[5][rg] * alv[5];
        float pl3 = acc[6][rg] * alv[6] + acc[7][rg] * alv[7];
        float pr0 = acc[0][rg] * arv[0] + acc[1][rg] * arv[1];
        float pr1 = acc[2][rg] * arv[2] + acc[3][rg] * arv[3];
        float pr2 = acc[4][rg] * arv[4] + acc[5][rg] * arv[5];
        float pr3 = acc[6][rg] * arv[6] + acc[7][rg] * arv[7];
#pragma unroll
        for (int m = 1; m <= 8; m <<= 1){
            pl0 += __shfl_xor(pl0, m, 64); pl1 += __shfl_xor(pl1, m, 64);
            pl2 += __shfl_xor(pl2, m, 64); pl3 += __shfl_xor(pl3, m, 64);
            pr0 += __shfl_xor(pr0, m, 64); pr1 += __shfl_xor(pr1, m, 64);
            pr2 += __shfl_xor(pr2, m, 64); pr3 += __shfl_xor(pr3, m, 64);
        }
        if (r == 0 && gr < N_NODES){
            *(float4*)(el + (size_t)gr * NHEAD) = make_float4(pl0, pl1, pl2, pl3);
            *(float4*)(er + (size_t)gr * NHEAD) = make_float4(pr0, pr1, pr2, pr3);
        }
    }
}

// ---------------- CSR build: degree + rank in one pass ----------------
__global__ void degree_kernel(const int* __restrict__ dst, int* __restrict__ deg,
                              int* __restrict__ rank){
    int e = blockIdx.x * blockDim.x + threadIdx.x;
    if (e < N_EDGES) rank[e] = atomicAdd(&deg[dst[e]], 1);
}

// hierarchical scan: part -> mid -> add
__global__ __launch_bounds__(256) void scan_part(const int* __restrict__ deg,
                                                 int* __restrict__ row_off,
                                                 int* __restrict__ blk_sums){
    __shared__ int lds[256];
    int tid = threadIdx.x;
    int i = blockIdx.x * 256 + tid;
    int v = (i < N_NODES) ? deg[i] : 0;
    int x = v;
    lds[tid] = x;
    __syncthreads();
    for (int off = 1; off < 256; off <<= 1){
        int t = (tid >= off) ? lds[tid - off] : 0;
        __syncthreads();
        x += t;
        lds[tid] = x;
        __syncthreads();
    }
    if (i < N_NODES) row_off[i] = x - v;          // local exclusive
    if (tid == 255) blk_sums[blockIdx.x] = x;     // block total
}

__global__ __launch_bounds__(256) void scan_mid(int* __restrict__ blk_sums,
                                                int* __restrict__ blk_off){
    __shared__ int lds[256];
    int tid = threadIdx.x;
    int v = (tid < NB_SCAN) ? blk_sums[tid] : 0;
    int x = v;
    lds[tid] = x;
    __syncthreads();
    for (int off = 1; off < 256; off <<= 1){
        int t = (tid >= off) ? lds[tid - off] : 0;
        __syncthreads();
        x += t;
        lds[tid] = x;
        __syncthreads();
    }
    blk_off[tid] = x - v;                          // exclusive
}

__global__ __launch_bounds__(256) void scan_add(int* __restrict__ row_off,
                                                const int* __restrict__ blk_off){
    int i = blockIdx.x * 256 + threadIdx.x;
    if (i < N_NODES) row_off[i] += blk_off[blockIdx.x];
    if (blockIdx.x == 0 && threadIdx.x == 0) row_off[N_NODES] = N_EDGES;
}

// ---------------- scatter: atomic-free, 4B per edge ----------------
__global__ void scatter_kernel(const int* __restrict__ src, const int* __restrict__ dst,
                               const int* __restrict__ rank, const int* __restrict__ row_off,
                               int* __restrict__ csr_src){
    int e = blockIdx.x * blockDim.x + threadIdx.x;
    if (e >= N_EDGES) return;
    csr_src[row_off[dst[e]] + rank[e]] = src[e];
}

// ---------------- aggregation: 16 nodes/block, one 16-lane group per node ----------------
__global__ __launch_bounds__(256) void aggregate_kernel(const unsigned short* __restrict__ ftb,
                                                        const int* __restrict__ csr_src,
                                                        const float* __restrict__ el,
                                                        const float* __restrict__ er,
                                                        const int* __restrict__ row_off,
                                                        const float* __restrict__ bias,
                                                        float* __restrict__ out){
    __shared__ float lw[4][4][16][4];   // [wave][grp][edge][head]
    __shared__ int   ls[4][4][16];      // [wave][grp][edge]

    const int wv   = threadIdx.x >> 6;
    const int lane = threadIdx.x & 63;
    const int grp  = lane >> 4;
    const int l    = lane & 15;
    const int h    = l >> 2;
    const int n    = blockIdx.x * 16 + wv * 4 + grp;     // grid 3125*16 = 50000 exact
    const int beg  = row_off[n], end = row_off[n + 1];
    const float4 ern = *(const float4*)(er + (size_t)n * NHEAD);

    float a[8];
#pragma unroll
    for (int k = 0; k < 8; ++k) a[k] = 0.f;
    float wsum = 0.f;

    for (int base = beg; base < end; base += 16){
        int cnt = end - base; if (cnt > 16) cnt = 16;
        if (l < cnt){
            int s_l = csr_src[base + l];
            float4 elv = *(const float4*)(el + (size_t)s_l * NHEAD);
            float4 w4;
            w4.x = __expf(lrelu(elv.x + ern.x));
            w4.y = __expf(lrelu(elv.y + ern.y));
            w4.z = __expf(lrelu(elv.z + ern.z));
            w4.w = __expf(lrelu(elv.w + ern.w));
            ls[wv][grp][l] = s_l;
            *(float4*)(&lw[wv][grp][l][0]) = w4;
        }
        asm volatile("s_waitcnt lgkmcnt(0)" ::: "memory");
        __builtin_amdgcn_sched_barrier(0);
        for (int j = 0; j < cnt; ++j){
            float w = lw[wv][grp][j][h];
            int   s = ls[wv][grp][j];
            uint4 f = *(const uint4*)(ftb + (size_t)s * HD + 8 * l);
            a[0] += w * bflo(f.x); a[1] += w * bfhi(f.x);
            a[2] += w * bflo(f.y); a[3] += w * bfhi(f.y);
            a[4] += w * bflo(f.z); a[5] += w * bfhi(f.z);
            a[6] += w * bflo(f.w); a[7] += w * bfhi(f.w);
            wsum += w;
        }
        __builtin_amdgcn_sched_barrier(0);        // keep next chunk's ds_write after reads
    }
    float inv = (end > beg) ? 1.f / wsum : 0.f;
    float4 b0 = *(const float4*)(bias + 8 * l);
    float4 b1 = *(const float4*)(bias + 8 * l + 4);
    float4 o0, o1;
    o0.x = a[0] * inv + b0.x; o0.y = a[1] * inv + b0.y;
    o0.z = a[2] * inv + b0.z; o0.w = a[3] * inv + b0.w;
    o1.x = a[4] * inv + b1.x; o1.y = a[5] * inv + b1.y;
    o1.z = a[6] * inv + b1.z; o1.w = a[7] * inv + b1.w;
    *(float4*)(out + (size_t)n * HD + 8 * l)     = o0;
    *(float4*)(out + (size_t)n * HD + 8 * l + 4) = o1;
}

extern "C" void kernel_launch(void* const* d_in, const int* in_sizes, int n_in,
                              void* d_out, int out_size, void* d_ws, size_t ws_size,
                              hipStream_t stream){
    const float* feat   = (const float*)d_in[0];
    const int*   src    = (const int*)  d_in[1];
    const int*   dst    = (const int*)  d_in[2];
    const float* W      = (const float*)d_in[3];
    const float* attn_l = (const float*)d_in[4];
    const float* attn_r = (const float*)d_in[5];
    const float* bias   = (const float*)d_in[6];
    float* out = (float*)d_out;
    char*  ws  = (char*)d_ws;

    // workspace layout (bytes)
    unsigned short* ftb = (unsigned short*)(ws + 0);   // 12,800,000
    float* el      = (float*)(ws + 12800000);   // 800,000
    float* er      = (float*)(ws + 13600000);   // 800,000
    int*   deg     = (int*)  (ws + 14400000);   // 200,000
    int*   rank    = (int*)  (ws + 14600000);   // 3,200,000
    int*   row_off = (int*)  (ws + 17800000);   // 200,004 (pad to 200,064)
    int*   csr_src = (int*)  (ws + 18000064);   // 3,200,000
    unsigned short* Wt_hi = (unsigned short*)(ws + 21200064);  // 65,536 (total ~21.3 MB)

    // transient aliases (scan-time only, csr_src not yet written):
    int* blk_sums = (int*)csr_src;
    int* blk_off  = blk_sums + 256;

    prep_kernel<<<NB_SCAN + 128, 256, 0, stream>>>(W, Wt_hi, deg);
    gemm_kernel<<<(N_NODES + GBM - 1) / GBM, 256, 0, stream>>>(feat, Wt_hi,
                                                               attn_l, attn_r, ftb, el, er);
    degree_kernel<<<(N_EDGES + 255) / 256, 256, 0, stream>>>(dst, deg, rank);
    scan_part<<<NB_SCAN, 256, 0, stream>>>(deg, row_off, blk_sums);
    scan_mid<<<1, 256, 0, stream>>>(blk_sums, blk_off);
    scan_add<<<NB_SCAN, 256, 0, stream>>>(row_off, blk_off);
    scatter_kernel<<<(N_EDGES + 255) / 256, 256, 0, stream>>>(src, dst, rank, row_off, csr_src);
    aggregate_kernel<<<N_NODES / 16, 256, 0, stream>>>(ftb, csr_src, el, er,
                                                       row_off, bias, out);
}